// Round 4
// baseline (353.010 us; speedup 1.0000x reference)
//
#include <hip/hip_runtime.h>

#define N_SEQ 256
#define T_LEN 1024
#define TP1   (T_LEN + 1)          // 1025
#define J_NUM 24
#define SEQ_ITEMS (TP1 * J_NUM)    // 24600 items per sequence
#define TOTAL_ITEMS (N_SEQ * SEQ_ITEMS)      // 6,297,600
#define GP_TOTAL (N_SEQ * TP1 * J_NUM * 3)   // global_pos element count

#define IPB 512                               // items per tile
#define NTILES (TOTAL_ITEMS / IPB)            // 12300 tiles
#define PGRID 1536                            // persistent blocks: 6/CU x 256 CU

// native 16B vector type accepted by __builtin_nontemporal_store
typedef float nfloat4 __attribute__((ext_vector_type(4)));

__device__ __forceinline__ void nt_store4(float4 v, float4* p) {
    nfloat4 nv = {v.x, v.y, v.z, v.w};
    __builtin_nontemporal_store(nv, (nfloat4*)p);
}

// ---------------------------------------------------------------------------
// Kernel A: per-sequence scans. 1 block per sequence, 1024 threads.
// Writes ws4[n*TP1+t] = (w, y, pos_x, pos_z).  (unchanged, proven)
// ---------------------------------------------------------------------------
__device__ __forceinline__ float block_scan_incl(float v, float* wsum, int tid) {
    const int lane = tid & 63;
    const int wid  = tid >> 6;
    #pragma unroll
    for (int off = 1; off < 64; off <<= 1) {
        float u = __shfl_up(v, off, 64);
        if (lane >= off) v += u;
    }
    if (lane == 63) wsum[wid] = v;
    __syncthreads();
    if (tid == 0) {
        float acc = 0.0f;
        #pragma unroll
        for (int i = 0; i < 16; ++i) { float t = wsum[i]; wsum[i] = acc; acc += t; }
    }
    __syncthreads();
    return v + wsum[wid];
}

extern "C" __global__ void __launch_bounds__(1024)
scan_kernel(const float* __restrict__ root_rvel,   // (N, T, 1, 1)
            const float* __restrict__ root_vel,    // (N, T, 1, 2)
            float4* __restrict__ ws4)              // (N, T+1) (w, y, px, pz)
{
    const int n   = blockIdx.x;
    const int tid = threadIdx.x;

    __shared__ float  r_s[TP1];
    __shared__ float2 quat_s[TP1];
    __shared__ float  ws_a[16], ws_b[16], ws_c[16];

    {
        float v = root_rvel[n * T_LEN + tid];
        float incl = block_scan_incl(v, ws_a, tid);
        if (tid == 0) r_s[0] = 0.0f;
        r_s[tid + 1] = incl;
    }
    __syncthreads();

    for (int idx = tid; idx < TP1; idx += 1024) {
        float r     = r_s[idx];
        float angle = fabsf(r);
        float half  = 0.5f * angle;
        float k = (angle < 1e-6f) ? (0.5f - angle * angle * (1.0f / 48.0f))
                                  : (__builtin_sinf(half) / angle);
        quat_s[idx] = make_float2(__builtin_cosf(half), r * k);
    }
    __syncthreads();

    {
        float2 vel = ((const float2*)root_vel)[n * T_LEN + tid];
        float2 q   = quat_s[tid];
        float  w = q.x, y = q.y;
        float t1x = w * vel.x + y * vel.y;
        float t1z = w * vel.y - y * vel.x;
        float ax  = t1x * w + t1z * y;
        float az  = t1z * w - t1x * y;
        float ix = block_scan_incl(ax, ws_b, tid);
        float iz = block_scan_incl(az, ws_c, tid);
        float2 qn = quat_s[tid + 1];
        ws4[n * TP1 + tid + 1] = make_float4(qn.x, qn.y, ix, iz);
        if (tid == 0) ws4[n * TP1] = make_float4(1.0f, 0.0f, 0.0f, 0.0f);
    }
}

// ---------------------------------------------------------------------------
// Per-item compute (math identical to rounds 0-2; verified absmax 1.76).
// bs >= 1 always (s0+s1+s2+s3 == 4), so relu / 0.1-floor are dropped.
// out_rot stored nontemporal (never re-read; don't pollute L3).
// ---------------------------------------------------------------------------
__device__ __forceinline__ void process_item(
    float a1x, float a1y, float a1z, float a2x, float a2y, float a2z,
    float vx,  float vy,  float vz,  float4 wq,
    float4* __restrict__ out_rot_addr, float* __restrict__ s_out3)
{
    const float w = wq.x, yq = wq.y;

    float inv1 = __builtin_amdgcn_rsqf(a1x * a1x + a1y * a1y + a1z * a1z);
    float b1x = a1x * inv1, b1y = a1y * inv1, b1z = a1z * inv1;
    float dp  = b1x * a2x + b1y * a2y + b1z * a2z;
    float px  = a2x - dp * b1x, py = a2y - dp * b1y, pz = a2z - dp * b1z;
    float inv2 = __builtin_amdgcn_rsqf(px * px + py * py + pz * pz);
    float b2x = px * inv2, b2y = py * inv2, b2z = pz * inv2;
    float b3x = b1y * b2z - b1z * b2y;
    float b3y = b1z * b2x - b1x * b2z;
    float b3z = b1x * b2y - b1y * b2x;

    float m00 = b1x, m01 = b1y, m02 = b1z;
    float m10 = b2x, m11 = b2y, m12 = b2z;
    float m20 = b3x, m21 = b3y, m22 = b3z;

    float s0 = 1.0f + m00 + m11 + m22;
    float s1 = 1.0f + m00 - m11 - m22;
    float s2 = 1.0f - m00 + m11 - m22;
    float s3 = 1.0f - m00 - m11 + m22;

    int best = 0; float bs = s0;
    if (s1 > bs) { best = 1; bs = s1; }
    if (s2 > bs) { best = 2; bs = s2; }
    if (s3 > bs) { best = 3; bs = s3; }

    float c0 = m21 - m12, c1 = m02 - m20, c2 = m10 - m01;
    float d0 = m10 + m01, d1 = m02 + m20, d2 = m21 + m12;

    float lw = best == 0 ? bs : (best == 1 ? c0 : (best == 2 ? c1 : c2));
    float lx = best == 0 ? c0 : (best == 1 ? bs : (best == 2 ? d0 : d1));
    float ly = best == 0 ? c1 : (best == 1 ? d0 : (best == 2 ? bs : d2));
    float lz = best == 0 ? c2 : (best == 1 ? d1 : (best == 2 ? d2 : bs));

    float invd = __builtin_amdgcn_rcpf(2.0f * __builtin_amdgcn_sqrtf(bs));
    lw *= invd; lx *= invd; ly *= invd; lz *= invd;

    float ow = w * lw - yq * ly;
    float ox = w * lx + yq * lz;
    float oy = w * ly + yq * lw;
    float oz = w * lz - yq * lx;
    if (ow < 0.0f) { ow = -ow; ox = -ox; oy = -oy; oz = -oz; }
    nt_store4(make_float4(ow, ox, oy, oz), out_rot_addr);

    float t1x = w * vx + yq * vz;
    float t1z = w * vz - yq * vx;
    s_out3[0] = t1x * w + t1z * yq + wq.z;
    s_out3[1] = (w * w + yq * yq) * vy;
    s_out3[2] = t1z * w - t1x * yq + wq.w;
}

// ---------------------------------------------------------------------------
// Kernel B: PERSISTENT blocks, cross-tile software pipeline (T14 pattern).
// Per iteration over a 512-item tile:
//   - issue tile t+1 global loads into registers (in flight during compute)
//   - compute tile t from LDS; out_rot direct NT store; out_pos -> s_out
//   - barrier
//   - drain out_pos(t) (NT); ds_write tile t+1 regs -> LDS
//   - barrier
// LDS = 24 KiB (rot 12 + pos 6 + out 6) -> 6 blocks/CU; launch_bounds(256,6)
// caps VGPR at 85 so 6 waves/SIMD are resident.
// ---------------------------------------------------------------------------
extern "C" __global__ void __launch_bounds__(256, 6)
elem_kernel(const float4* __restrict__ rot4,      // local_rot as float4
            const float4* __restrict__ pos4,      // local_pos as float4
            const float4* __restrict__ ws4,       // (N, T+1)
            float4* __restrict__ out_rot4,        // out_rot as float4
            float4* __restrict__ out_pos4)        // out_pos as float4
{
    __shared__ float4 s_rot4[768];   // 12 KiB: 512 items x 6 floats
    __shared__ float4 s_pos4[384];   //  6 KiB: 512 items x 3 floats
    __shared__ float4 s_out4[384];   //  6 KiB: 512 items x 3 floats
    float* s_rot = (float*)s_rot4;
    float* s_pos = (float*)s_pos4;
    float* s_out = (float*)s_out4;

    const int tid = threadIdx.x;
    unsigned tile = blockIdx.x;

    float4 nr0, nr1, nr2, np0, np1, nwq0, nwq1;

    // ---- prologue: load + stage first tile ----
    {
        const float4* rb = rot4 + (size_t)tile * 768;
        nr0 = rb[tid]; nr1 = rb[tid + 256]; nr2 = rb[tid + 512];
        const float4* pb = pos4 + (size_t)tile * 384;
        np0 = pb[tid];
        np1 = (tid < 128) ? pb[tid + 256] : make_float4(0.f, 0.f, 0.f, 0.f);
        unsigned a0 = tile * (unsigned)IPB + (unsigned)tid, a1 = a0 + 256u;
        unsigned q0 = a0 / (unsigned)SEQ_ITEMS, t0 = (a0 - q0 * (unsigned)SEQ_ITEMS) / (unsigned)J_NUM;
        unsigned q1 = a1 / (unsigned)SEQ_ITEMS, t1 = (a1 - q1 * (unsigned)SEQ_ITEMS) / (unsigned)J_NUM;
        nwq0 = ws4[q0 * (unsigned)TP1 + t0];
        nwq1 = ws4[q1 * (unsigned)TP1 + t1];
    }
    s_rot4[tid] = nr0; s_rot4[tid + 256] = nr1; s_rot4[tid + 512] = nr2;
    s_pos4[tid] = np0; if (tid < 128) s_pos4[tid + 256] = np1;
    float4 cwq0 = nwq0, cwq1 = nwq1;
    __syncthreads();

    for (;;) {
        const unsigned next = tile + (unsigned)PGRID;
        const bool has = next < (unsigned)NTILES;

        // ---- issue next-tile loads (hidden under compute below) ----
        if (has) {
            const float4* rb = rot4 + (size_t)next * 768;
            nr0 = rb[tid]; nr1 = rb[tid + 256]; nr2 = rb[tid + 512];
            const float4* pb = pos4 + (size_t)next * 384;
            np0 = pb[tid];
            if (tid < 128) np1 = pb[tid + 256];
            unsigned a0 = next * (unsigned)IPB + (unsigned)tid, a1 = a0 + 256u;
            unsigned q0 = a0 / (unsigned)SEQ_ITEMS, t0 = (a0 - q0 * (unsigned)SEQ_ITEMS) / (unsigned)J_NUM;
            unsigned q1 = a1 / (unsigned)SEQ_ITEMS, t1 = (a1 - q1 * (unsigned)SEQ_ITEMS) / (unsigned)J_NUM;
            nwq0 = ws4[q0 * (unsigned)TP1 + t0];
            nwq1 = ws4[q1 * (unsigned)TP1 + t1];
        }

        // ---- compute current tile from LDS ----
        {
            const unsigned a0 = tile * (unsigned)IPB + (unsigned)tid;
            const unsigned a1 = a0 + 256u;
            const float2* s_rot2 = (const float2*)s_rot;
            const int L0 = tid, L1 = tid + 256;
            float2 ra0 = s_rot2[3 * L0 + 0];
            float2 rb0 = s_rot2[3 * L0 + 1];
            float2 rc0 = s_rot2[3 * L0 + 2];
            float2 ra1 = s_rot2[3 * L1 + 0];
            float2 rb1 = s_rot2[3 * L1 + 1];
            float2 rc1 = s_rot2[3 * L1 + 2];
            float p0x = s_pos[3 * L0 + 0], p0y = s_pos[3 * L0 + 1], p0z = s_pos[3 * L0 + 2];
            float p1x = s_pos[3 * L1 + 0], p1y = s_pos[3 * L1 + 1], p1z = s_pos[3 * L1 + 2];

            process_item(ra0.x, ra0.y, rb0.x, rb0.y, rc0.x, rc0.y,
                         p0x, p0y, p0z, cwq0, &out_rot4[a0], &s_out[3 * L0]);
            process_item(ra1.x, ra1.y, rb1.x, rb1.y, rc1.x, rc1.y,
                         p1x, p1y, p1z, cwq1, &out_rot4[a1], &s_out[3 * L1]);
        }

        __syncthreads();   // all LDS reads of tile done; s_out complete

        // ---- drain out_pos(tile) + stage tile t+1 into LDS ----
        {
            float4* opb = out_pos4 + (size_t)tile * 384;
            nt_store4(s_out4[tid], &opb[tid]);
            if (tid < 128) nt_store4(s_out4[tid + 256], &opb[tid + 256]);
        }
        if (!has) break;
        s_rot4[tid] = nr0; s_rot4[tid + 256] = nr1; s_rot4[tid + 512] = nr2;
        s_pos4[tid] = np0; if (tid < 128) s_pos4[tid + 256] = np1;
        cwq0 = nwq0; cwq1 = nwq1;
        __syncthreads();   // next tile staged; safe to compute (and overwrite s_out)
        tile = next;
    }
}

extern "C" void kernel_launch(void* const* d_in, const int* in_sizes, int n_in,
                              void* d_out, int out_size, void* d_ws, size_t ws_size,
                              hipStream_t stream) {
    (void)in_sizes; (void)n_in; (void)ws_size; (void)out_size;
    const float* root_rvel = (const float*)d_in[0];
    const float* local_pos = (const float*)d_in[1];
    const float* local_rot = (const float*)d_in[2];
    const float* root_vel  = (const float*)d_in[3];
    float* out = (float*)d_out;

    float4* ws4 = (float4*)d_ws;   // N*TP1 float4 = 4.2 MB

    scan_kernel<<<N_SEQ, 1024, 0, stream>>>(root_rvel, root_vel, ws4);

    elem_kernel<<<PGRID, 256, 0, stream>>>(
        (const float4*)local_rot, (const float4*)local_pos, ws4,
        (float4*)(out + GP_TOTAL),   // out_rot
        (float4*)out);               // out_pos
}

// Round 5
// 337.831 us; speedup vs baseline: 1.0449x; 1.0449x over previous
//
#include <hip/hip_runtime.h>

#define N_SEQ 256
#define T_LEN 1024
#define TP1   (T_LEN + 1)          // 1025
#define J_NUM 24
#define SEQ_ITEMS (TP1 * J_NUM)    // 24600 items per sequence
#define TOTAL_ITEMS (N_SEQ * SEQ_ITEMS)      // 6,297,600
#define GP_TOTAL (N_SEQ * TP1 * J_NUM * 3)   // global_pos element count

#define IPB 512                               // items per block
#define NBLOCKS_B (TOTAL_ITEMS / IPB)         // 12300 blocks

// ---------------------------------------------------------------------------
// Kernel A: per-sequence scans. 1 block per sequence, 1024 threads.
// Writes ws4[n*TP1+t] = (w, y, pos_x, pos_z).  (unchanged, proven)
// ---------------------------------------------------------------------------
__device__ __forceinline__ float block_scan_incl(float v, float* wsum, int tid) {
    const int lane = tid & 63;
    const int wid  = tid >> 6;
    #pragma unroll
    for (int off = 1; off < 64; off <<= 1) {
        float u = __shfl_up(v, off, 64);
        if (lane >= off) v += u;
    }
    if (lane == 63) wsum[wid] = v;
    __syncthreads();
    if (tid == 0) {
        float acc = 0.0f;
        #pragma unroll
        for (int i = 0; i < 16; ++i) { float t = wsum[i]; wsum[i] = acc; acc += t; }
    }
    __syncthreads();
    return v + wsum[wid];
}

extern "C" __global__ void __launch_bounds__(1024)
scan_kernel(const float* __restrict__ root_rvel,   // (N, T, 1, 1)
            const float* __restrict__ root_vel,    // (N, T, 1, 2)
            float4* __restrict__ ws4)              // (N, T+1) (w, y, px, pz)
{
    const int n   = blockIdx.x;
    const int tid = threadIdx.x;

    __shared__ float  r_s[TP1];
    __shared__ float2 quat_s[TP1];
    __shared__ float  ws_a[16], ws_b[16], ws_c[16];

    {
        float v = root_rvel[n * T_LEN + tid];
        float incl = block_scan_incl(v, ws_a, tid);
        if (tid == 0) r_s[0] = 0.0f;
        r_s[tid + 1] = incl;
    }
    __syncthreads();

    for (int idx = tid; idx < TP1; idx += 1024) {
        float r     = r_s[idx];
        float angle = fabsf(r);
        float half  = 0.5f * angle;
        float k = (angle < 1e-6f) ? (0.5f - angle * angle * (1.0f / 48.0f))
                                  : (__builtin_sinf(half) / angle);
        quat_s[idx] = make_float2(__builtin_cosf(half), r * k);
    }
    __syncthreads();

    {
        float2 vel = ((const float2*)root_vel)[n * T_LEN + tid];
        float2 q   = quat_s[tid];
        float  w = q.x, y = q.y;
        float t1x = w * vel.x + y * vel.y;
        float t1z = w * vel.y - y * vel.x;
        float ax  = t1x * w + t1z * y;
        float az  = t1z * w - t1x * y;
        float ix = block_scan_incl(ax, ws_b, tid);
        float iz = block_scan_incl(az, ws_c, tid);
        float2 qn = quat_s[tid + 1];
        ws4[n * TP1 + tid + 1] = make_float4(qn.x, qn.y, ix, iz);
        if (tid == 0) ws4[n * TP1] = make_float4(1.0f, 0.0f, 0.0f, 0.0f);
    }
}

// ---------------------------------------------------------------------------
// Rot math (identical numerics to verified rounds 0-2).
// bs >= 1 always (s0+s1+s2+s3 == 4), so relu / 0.1-floor are dropped.
// ---------------------------------------------------------------------------
__device__ __forceinline__ float4 rot_item(
    float a1x, float a1y, float a1z, float a2x, float a2y, float a2z,
    float w, float yq)
{
    float inv1 = __builtin_amdgcn_rsqf(a1x * a1x + a1y * a1y + a1z * a1z);
    float b1x = a1x * inv1, b1y = a1y * inv1, b1z = a1z * inv1;
    float dp  = b1x * a2x + b1y * a2y + b1z * a2z;
    float px  = a2x - dp * b1x, py = a2y - dp * b1y, pz = a2z - dp * b1z;
    float inv2 = __builtin_amdgcn_rsqf(px * px + py * py + pz * pz);
    float b2x = px * inv2, b2y = py * inv2, b2z = pz * inv2;
    float b3x = b1y * b2z - b1z * b2y;
    float b3y = b1z * b2x - b1x * b2z;
    float b3z = b1x * b2y - b1y * b2x;

    float m00 = b1x, m01 = b1y, m02 = b1z;
    float m10 = b2x, m11 = b2y, m12 = b2z;
    float m20 = b3x, m21 = b3y, m22 = b3z;

    float s0 = 1.0f + m00 + m11 + m22;
    float s1 = 1.0f + m00 - m11 - m22;
    float s2 = 1.0f - m00 + m11 - m22;
    float s3 = 1.0f - m00 - m11 + m22;

    int best = 0; float bs = s0;
    if (s1 > bs) { best = 1; bs = s1; }
    if (s2 > bs) { best = 2; bs = s2; }
    if (s3 > bs) { best = 3; bs = s3; }

    float c0 = m21 - m12, c1 = m02 - m20, c2 = m10 - m01;
    float d0 = m10 + m01, d1 = m02 + m20, d2 = m21 + m12;

    float lw = best == 0 ? bs : (best == 1 ? c0 : (best == 2 ? c1 : c2));
    float lx = best == 0 ? c0 : (best == 1 ? bs : (best == 2 ? d0 : d1));
    float ly = best == 0 ? c1 : (best == 1 ? d0 : (best == 2 ? bs : d2));
    float lz = best == 0 ? c2 : (best == 1 ? d1 : (best == 2 ? d2 : bs));

    float invd = __builtin_amdgcn_rcpf(2.0f * __builtin_amdgcn_sqrtf(bs));
    lw *= invd; lx *= invd; ly *= invd; lz *= invd;

    float ow = w * lw - yq * ly;
    float ox = w * lx + yq * lz;
    float oy = w * ly + yq * lw;
    float oz = w * lz - yq * lx;
    if (ow < 0.0f) { ow = -ow; ox = -ox; oy = -oy; oz = -oz; }
    return make_float4(ow, ox, oy, oz);
}

// ---------------------------------------------------------------------------
// Kernel B1: rotations only. 512 items / 256-thread block, 2 items/thread.
// Streams: read local_rot (151 MB), write out_rot (101 MB). ONE barrier.
//   stage: 3 coalesced float4 loads/thread -> LDS (linear, ds_write_b128)
//   read:  3x float2 per item, stride 24 B (2-way bank alias = free)
//   write: direct coalesced float4 per item
// LDS 12 KiB -> 8 blocks/CU (wave cap).
// ---------------------------------------------------------------------------
extern "C" __global__ void __launch_bounds__(256, 8)
rot_kernel(const float4* __restrict__ rot4,      // local_rot as float4
           const float4* __restrict__ ws4,      // (N, T+1)
           float4* __restrict__ out_rot4)       // out_rot as float4
{
    __shared__ float4 s_rot4[768];   // 12 KiB: 512 items x 6 floats
    const float2* s_rot2 = (const float2*)s_rot4;

    const int tid = threadIdx.x;
    const unsigned blk = blockIdx.x;

    // stage (coalesced, linear)
    {
        const float4* rb = rot4 + (size_t)blk * 768;
        s_rot4[tid]       = rb[tid];
        s_rot4[tid + 256] = rb[tid + 256];
        s_rot4[tid + 512] = rb[tid + 512];
    }

    // ws gather (independent of LDS)
    const unsigned a0 = blk * (unsigned)IPB + (unsigned)tid;
    const unsigned a1 = a0 + 256u;
    const unsigned q0 = a0 / (unsigned)SEQ_ITEMS;
    const unsigned t0 = (a0 - q0 * (unsigned)SEQ_ITEMS) / (unsigned)J_NUM;
    const unsigned q1 = a1 / (unsigned)SEQ_ITEMS;
    const unsigned t1 = (a1 - q1 * (unsigned)SEQ_ITEMS) / (unsigned)J_NUM;
    const float4 wq0 = ws4[q0 * (unsigned)TP1 + t0];
    const float4 wq1 = ws4[q1 * (unsigned)TP1 + t1];

    __syncthreads();

    const int L0 = tid, L1 = tid + 256;
    float2 ra0 = s_rot2[3 * L0 + 0];
    float2 rb0 = s_rot2[3 * L0 + 1];
    float2 rc0 = s_rot2[3 * L0 + 2];
    float2 ra1 = s_rot2[3 * L1 + 0];
    float2 rb1 = s_rot2[3 * L1 + 1];
    float2 rc1 = s_rot2[3 * L1 + 2];

    out_rot4[a0] = rot_item(ra0.x, ra0.y, rb0.x, rb0.y, rc0.x, rc0.y, wq0.x, wq0.y);
    out_rot4[a1] = rot_item(ra1.x, ra1.y, rb1.x, rb1.y, rc1.x, rc1.y, wq1.x, wq1.y);
}

// ---------------------------------------------------------------------------
// Kernel B2: positions only. 512 items / 256-thread block, 2 items/thread.
// Streams: read local_pos (76 MB), write out_pos (76 MB). Two barriers.
// LDS 12 KiB (pos 6 + out 6) -> 8 blocks/CU (wave cap).
// ---------------------------------------------------------------------------
extern "C" __global__ void __launch_bounds__(256, 8)
pos_kernel(const float4* __restrict__ pos4,     // local_pos as float4
           const float4* __restrict__ ws4,     // (N, T+1)
           float4* __restrict__ out_pos4)      // out_pos as float4
{
    __shared__ float4 s_pos4[384];   // 6 KiB: 512 items x 3 floats
    __shared__ float4 s_out4[384];   // 6 KiB
    float* s_pos = (float*)s_pos4;
    float* s_out = (float*)s_out4;

    const int tid = threadIdx.x;
    const unsigned blk = blockIdx.x;

    // stage (coalesced, linear)
    {
        const float4* pb = pos4 + (size_t)blk * 384;
        s_pos4[tid] = pb[tid];
        if (tid < 128) s_pos4[tid + 256] = pb[tid + 256];
    }

    // ws gather
    const unsigned a0 = blk * (unsigned)IPB + (unsigned)tid;
    const unsigned a1 = a0 + 256u;
    const unsigned q0 = a0 / (unsigned)SEQ_ITEMS;
    const unsigned t0 = (a0 - q0 * (unsigned)SEQ_ITEMS) / (unsigned)J_NUM;
    const unsigned q1 = a1 / (unsigned)SEQ_ITEMS;
    const unsigned t1 = (a1 - q1 * (unsigned)SEQ_ITEMS) / (unsigned)J_NUM;
    const float4 wq0 = ws4[q0 * (unsigned)TP1 + t0];
    const float4 wq1 = ws4[q1 * (unsigned)TP1 + t1];

    __syncthreads();

    const int L0 = tid, L1 = tid + 256;
    {
        float vx = s_pos[3 * L0 + 0], vy = s_pos[3 * L0 + 1], vz = s_pos[3 * L0 + 2];
        float w = wq0.x, yq = wq0.y;
        float t1x = w * vx + yq * vz;
        float t1z = w * vz - yq * vx;
        s_out[3 * L0 + 0] = t1x * w + t1z * yq + wq0.z;
        s_out[3 * L0 + 1] = (w * w + yq * yq) * vy;
        s_out[3 * L0 + 2] = t1z * w - t1x * yq + wq0.w;
    }
    {
        float vx = s_pos[3 * L1 + 0], vy = s_pos[3 * L1 + 1], vz = s_pos[3 * L1 + 2];
        float w = wq1.x, yq = wq1.y;
        float t1x = w * vx + yq * vz;
        float t1z = w * vz - yq * vx;
        s_out[3 * L1 + 0] = t1x * w + t1z * yq + wq1.z;
        s_out[3 * L1 + 1] = (w * w + yq * yq) * vy;
        s_out[3 * L1 + 2] = t1z * w - t1x * yq + wq1.w;
    }

    __syncthreads();

    // drain (coalesced)
    float4* opb = out_pos4 + (size_t)blk * 384;
    opb[tid] = s_out4[tid];
    if (tid < 128) opb[tid + 256] = s_out4[tid + 256];
}

extern "C" void kernel_launch(void* const* d_in, const int* in_sizes, int n_in,
                              void* d_out, int out_size, void* d_ws, size_t ws_size,
                              hipStream_t stream) {
    (void)in_sizes; (void)n_in; (void)ws_size; (void)out_size;
    const float* root_rvel = (const float*)d_in[0];
    const float* local_pos = (const float*)d_in[1];
    const float* local_rot = (const float*)d_in[2];
    const float* root_vel  = (const float*)d_in[3];
    float* out = (float*)d_out;

    float4* ws4 = (float4*)d_ws;   // N*TP1 float4 = 4.2 MB

    scan_kernel<<<N_SEQ, 1024, 0, stream>>>(root_rvel, root_vel, ws4);

    rot_kernel<<<NBLOCKS_B, 256, 0, stream>>>(
        (const float4*)local_rot, ws4, (float4*)(out + GP_TOTAL));

    pos_kernel<<<NBLOCKS_B, 256, 0, stream>>>(
        (const float4*)local_pos, ws4, (float4*)out);
}